// Round 10
// baseline (150.472 us; speedup 1.0000x reference)
//
#include <hip/hip_runtime.h>
#include <hip/hip_bf16.h>

// Problem dims
#define B_    2
#define CIN   128
#define COUT  128
#define DD    16
#define HH    32
#define WW    32
// out strides: [b][co][d2][h2][w2]
#define OS_H2 64
#define OS_D2 (64*64)
#define OS_CO (32*64*64)
#define OS_B  (COUT*OS_CO)

// ci-innermost padded bf16 array: XT[b][d' 18][h' 34][w' 34][ci 128]
// interior at d':1..16, h':1..32, w':1..32 (all +1 pad shift)
#define XT_CIB 256                     // 128 ci * 2B
#define XT_H   (34*XT_CIB)             // 8704  (w' stride... per h' row of 34 w')
#define XT_D   (34*XT_H)               // 295936
#define XT_B   (18*XT_D)               // 5326848
#define XT_BYTES ((size_t)B_*XT_B)     // 10,653,696
#define AFOLD_BYTES (8*32*8*64*16)     // 2 MiB

typedef __attribute__((ext_vector_type(8))) short        short8;
typedef __attribute__((ext_vector_type(4))) float        floatx4;
typedef __attribute__((ext_vector_type(4))) float        float4v;
typedef __attribute__((ext_vector_type(4))) unsigned int uint4v;

static __device__ __forceinline__ unsigned short f2bf(float f) {
    union { __hip_bfloat16 h; unsigned short u; } cv;
    cv.h = __float2bfloat16(f);
    return cv.u;
}

// ---------------------------------------------------------------------------
// Kernel 1: fold weights, K-REORDERED: k = tap*128 + ci.
// Afold[p][ks][ct][lane][j]: tap = ks>>2, ci = (ks&3)*32 + (lane>>4)*8 + j,
// co = ct*16 + (lane&15).  Each thread folds ONE tap for 8 consecutive ci.
// Per-dim fold (verified r1-r9): e=0: t0->{0}, t1->{1,2}; e=1: t0->{0,1}, t1->{2}
// ---------------------------------------------------------------------------
__global__ __launch_bounds__(256) void fold_kernel(const float* __restrict__ Wk,
                                                   unsigned short* __restrict__ Afold) {
    const int t = blockIdx.x * 256 + threadIdx.x;   // 0 .. 131071
    const int p  = t >> 14;
    const int ks = (t >> 9) & 31;
    const int ct = (t >> 6) & 7;
    const int l  = t & 63;
    const int co  = ct * 16 + (l & 15);
    const int ci0 = (ks & 3) * 32 + (l >> 4) * 8;
    const int tap = ks >> 2;
    const int td = (tap >> 2) & 1, th = (tap >> 1) & 1, tw = tap & 1;
    const int ed = (p >> 2) & 1,  eh = (p >> 1) & 1,  ew = p & 1;

    const int dlo = ed ? (td ? 2 : 0) : (td ? 1 : 0);
    const int dhi = ed ? (td ? 2 : 1) : (td ? 2 : 0);
    const int hlo = eh ? (th ? 2 : 0) : (th ? 1 : 0);
    const int hhi = eh ? (th ? 2 : 1) : (th ? 2 : 0);
    const int wlo = ew ? (tw ? 2 : 0) : (tw ? 1 : 0);
    const int whi = ew ? (tw ? 2 : 1) : (tw ? 2 : 0);

    short8 pk;
    #pragma unroll
    for (int j = 0; j < 8; ++j) {
        const float* w = Wk + (co * CIN + ci0 + j) * 27;
        float s = 0.f;
        for (int kd = dlo; kd <= dhi; ++kd)
            for (int kh = hlo; kh <= hhi; ++kh)
                for (int kw = wlo; kw <= whi; ++kw)
                    s += w[kd * 9 + kh * 3 + kw];
        pk[j] = (short)f2bf(s);
    }
    reinterpret_cast<short8*>(Afold)[t] = pk;
}

// ---------------------------------------------------------------------------
// Kernel 2: convert+pad+TRANSPOSE x -> XT[b][d'][h'][w'][ci] (ci innermost).
// One block per (b,d,h); LDS tile transpose; borders pre-zeroed by memset.
// ---------------------------------------------------------------------------
__global__ __launch_bounds__(256) void pad_kernel(const float* __restrict__ x,
                                                  char* __restrict__ xt) {
    __shared__ unsigned short lds_t[32][128];   // [w][ci], 8 KiB
    const int bx = blockIdx.x;                  // 0..1023
    const int b = bx >> 9, d = (bx >> 5) & 15, h = bx & 31;
    const int t = threadIdx.x;

    #pragma unroll
    for (int i = 0; i < 4; ++i) {
        const int u  = t + 256 * i;             // 0..1023
        const int ci = u >> 3, wg = u & 7;
        const float4v v = *reinterpret_cast<const float4v*>(
            x + (size_t)((b * CIN + ci) * DD + d) * (HH * WW) + h * WW + wg * 4);
        #pragma unroll
        for (int k = 0; k < 4; ++k)
            lds_t[wg * 4 + k][ci] = f2bf(v[k]);
    }
    __syncthreads();
    char* ob = xt + (size_t)b * XT_B + (d + 1) * XT_D + (h + 1) * XT_H + XT_CIB;
    #pragma unroll
    for (int i = 0; i < 2; ++i) {
        const int u = t + 256 * i;              // 0..511
        const int w = u >> 4, grp = u & 15;
        *reinterpret_cast<uint4v*>(ob + w * XT_CIB + grp * 16) =
            *reinterpret_cast<const uint4v*>(&lds_t[w][grp * 8]);
    }
}

// ---------------------------------------------------------------------------
// Kernel 3: per-parity implicit GEMM, tap-major K.
//   Chunk kc (64 k) = tap (kc>>1), ci-half (kc&1).  Staging = 4 x
//   global_load_lds width-16 per wave per chunk (lane-linear LDS [g][n][16B],
//   zero VGPR staging, zero bank conflicts).  Triple-buffered LDS, ONE raw
//   barrier per chunk, counted vmcnt (12 mid-loop / 8 last), never drained.
// ---------------------------------------------------------------------------
__global__ __launch_bounds__(256, 3) void upconv_mfma(
    const char* __restrict__ xt,
    const unsigned short* __restrict__ Afold,
    const float* __restrict__ bias,
    float* __restrict__ out)
{
    __shared__ short Bt[3][8192];   // 3 x 16 KiB
    char* bufs[3] = { reinterpret_cast<char*>(&Bt[0][0]),
                      reinterpret_cast<char*>(&Bt[1][0]),
                      reinterpret_cast<char*>(&Bt[2][0]) };

    const int tid  = threadIdx.x;
    const int wave = tid >> 6;
    const int lane = tid & 63;

    const int d      = blockIdx.x >> 3;
    const int h_base = (blockIdx.x & 7) * 4;
    const int p      = blockIdx.y;
    const int b      = blockIdx.z;
    const int ed = (p >> 2) & 1, eh = (p >> 1) & 1, ew = p & 1;

    // ---- staging geometry: 4 units per wave, unit u -> (g, nhalf) ----
    size_t srcoff[4];
    int    dstb[4];
    #pragma unroll
    for (int u = 0; u < 4; ++u) {
        const int g  = wave * 2 + (u >> 1);
        const int nh = u & 1;
        const int n  = nh * 64 + lane;
        const int hl = n >> 5, wl = n & 31;
        srcoff[u] = (size_t)b * XT_B + (size_t)(d + ed) * XT_D
                  + (size_t)(h_base + hl + eh) * XT_H
                  + (size_t)(wl + ew) * XT_CIB + g * 16;
        dstb[u] = g * 2048 + nh * 1024;          // wave-uniform
    }

    // ---- MFMA-read geometry: LDS byte = (ksl*4+lane4)*2048 + n*16 ----
    const int co0 = (wave >> 1) * 64;
    const int n0  = (wave & 1) * 64;
    const int ct0 = (wave >> 1) * 4;
    int raddr[2][4];
    #pragma unroll
    for (int ksl = 0; ksl < 2; ++ksl)
        #pragma unroll
        for (int nt = 0; nt < 4; ++nt)
            raddr[ksl][nt] = (ksl * 4 + (lane >> 4)) * 2048
                           + (n0 + nt * 16 + (lane & 15)) * 16;

    floatx4 acc[4][4];
    #pragma unroll
    for (int i = 0; i < 4; ++i)
        #pragma unroll
        for (int j = 0; j < 4; ++j)
            acc[i][j] = (floatx4){0.f, 0.f, 0.f, 0.f};

    const short8* Ap = reinterpret_cast<const short8*>(Afold);

    #define STAGE(kc, bufc)                                                     \
        do {                                                                    \
            const int t_  = (kc) >> 1;                                          \
            const int OFF = ((t_ >> 2) & 1) * XT_D + ((t_ >> 1) & 1) * XT_H     \
                          + (t_ & 1) * XT_CIB + ((kc) & 1) * 128;               \
            _Pragma("unroll")                                                   \
            for (int u = 0; u < 4; ++u)                                         \
                __builtin_amdgcn_global_load_lds(                               \
                    (const __attribute__((address_space(1))) void*)             \
                        (xt + srcoff[u] + OFF),                                 \
                    (__attribute__((address_space(3))) void*)                   \
                        ((bufc) + dstb[u]),                                     \
                    16, 0, 0);                                                  \
        } while (0)

    #define BODY(kc)                                                            \
        do {                                                                    \
            short8 a[2][4];                                                     \
            _Pragma("unroll")                                                   \
            for (int ksl = 0; ksl < 2; ++ksl)                                   \
                _Pragma("unroll")                                               \
                for (int ct = 0; ct < 4; ++ct)                                  \
                    a[ksl][ct] = Ap[(size_t)(((p) * 32 + (kc) * 2 + ksl) * 8    \
                                             + ct0 + ct) * 64 + lane];          \
            if ((kc) < 15) STAGE((kc) + 1, bufs[((kc) + 1) % 3]);               \
            __builtin_amdgcn_sched_barrier(0);                                  \
            if ((kc) < 15) asm volatile("s_waitcnt vmcnt(12)" ::: "memory");    \
            else           asm volatile("s_waitcnt vmcnt(8)"  ::: "memory");    \
            __builtin_amdgcn_sched_barrier(0);                                  \
            __builtin_amdgcn_s_barrier();                                       \
            char* bufc = bufs[(kc) % 3];                                        \
            __builtin_amdgcn_s_setprio(1);                                      \
            _Pragma("unroll")                                                   \
            for (int ksl = 0; ksl < 2; ++ksl) {                                 \
                short8 bfr[4];                                                  \
                _Pragma("unroll")                                               \
                for (int nt = 0; nt < 4; ++nt)                                  \
                    bfr[nt] = *reinterpret_cast<const short8*>(                 \
                        bufc + raddr[ksl][nt]);                                 \
                _Pragma("unroll")                                               \
                for (int ct = 0; ct < 4; ++ct)                                  \
                    _Pragma("unroll")                                           \
                    for (int nt = 0; nt < 4; ++nt)                              \
                        acc[ct][nt] = __builtin_amdgcn_mfma_f32_16x16x32_bf16(  \
                            a[ksl][ct], bfr[nt], acc[ct][nt], 0, 0, 0);         \
            }                                                                   \
            __builtin_amdgcn_s_setprio(0);                                      \
        } while (0)

    STAGE(0, bufs[0]);
    #pragma unroll
    for (int kc = 0; kc < 16; ++kc) BODY(kc);
    #undef BODY
    #undef STAGE

    // ---- epilogue: add bias, scatter to upsampled layout (r7-verified) ----
    float* ob = out + (size_t)b * OS_B + (size_t)(2 * d + ed) * OS_D2;
    #pragma unroll
    for (int ct = 0; ct < 4; ++ct) {
        #pragma unroll
        for (int j = 0; j < 4; ++j) {
            const int co = co0 + ct * 16 + (lane >> 4) * 4 + j;
            const float bv = bias[co];
            #pragma unroll
            for (int nt = 0; nt < 4; ++nt) {
                const int n  = n0 + nt * 16 + (lane & 15);
                const int hh = n >> 5, wl = n & 31;
                const int h2 = 2 * (h_base + hh) + eh;
                const int w2 = 2 * wl + ew;
                ob[(size_t)co * OS_CO + h2 * OS_H2 + w2] = acc[ct][nt][j] + bv;
            }
        }
    }
}

extern "C" void kernel_launch(void* const* d_in, const int* in_sizes, int n_in,
                              void* d_out, int out_size, void* d_ws, size_t ws_size,
                              hipStream_t stream) {
    const float* x    = (const float*)d_in[0];
    const float* Wk   = (const float*)d_in[1];
    const float* bias = (const float*)d_in[2];
    float* out        = (float*)d_out;

    unsigned short* Afold = (unsigned short*)d_ws;
    char* xt = (char*)d_ws + AFOLD_BYTES;

    hipMemsetAsync(xt, 0, XT_BYTES, stream);
    pad_kernel<<<1024, 256, 0, stream>>>(x, xt);
    fold_kernel<<<512, 256, 0, stream>>>(Wk, Afold);

    dim3 grid(DD * 8, 8, B_);   // (128, 8 parity, 2 batch)
    upconv_mfma<<<grid, 256, 0, stream>>>(xt, Afold, bias, out);
}